// Round 1
// baseline (503.864 us; speedup 1.0000x reference)
//
#include <hip/hip_runtime.h>

#define OBS_T 20
#define HID 128
#define NGATE 512
#define MB 16          // batch rows per block
#define HSTR 136       // hbuf row stride in bf16 (272B = 17*16B)

typedef __bf16 bf16x8 __attribute__((ext_vector_type(8)));
typedef __bf16 bf16x4 __attribute__((ext_vector_type(4)));
typedef float f32x4 __attribute__((ext_vector_type(4)));
typedef float f32x2 __attribute__((ext_vector_type(2)));

__device__ __forceinline__ float fast_rcp(float x) { return __builtin_amdgcn_rcpf(x); }
#if __has_builtin(__builtin_amdgcn_exp2f)
__device__ __forceinline__ float exp2_hw(float x) { return __builtin_amdgcn_exp2f(x); }
#else
__device__ __forceinline__ float exp2_hw(float x) { return __expf(x * 0.69314718056f); }
#endif
#define LOG2E 1.442695041f

// gate scale: preacts arrive PRE-SCALED by s_q so exp2 needs no mul.
// s_q = -LOG2E for i,f,o ; -2*LOG2E for g (since tanh uses e^{-2x})
__device__ __host__ __forceinline__ float gate_scale(int q) {
  return (q == 2) ? (-2.0f * LOG2E) : (-LOG2E);
}

// ---- prep 1: fold embedding into rank-2 + bias, gate-major permutation ----
// gate row r = q*128 + j (torch i,f,g,o). np = (j>>4)*64 + q*16 + (j&15)
// SCALAR tables (r8/r10-proven; float4-packed variant failed twice — banned).
// Values pre-scaled by gate_scale(q).
__global__ void prep_vec(const float* __restrict__ W_emb, const float* __restrict__ b_emb,
                         const float* __restrict__ W_ih, const float* __restrict__ b_ih,
                         const float* __restrict__ b_hh,
                         float* __restrict__ biasp, float* __restrict__ wx0p,
                         float* __restrict__ wx1p) {
  int r = blockIdx.x * blockDim.x + threadIdx.x;
  if (r >= NGATE) return;
  float s0 = 0.f, s1 = 0.f, sb = 0.f;
  for (int d = 0; d < 64; ++d) {
    float w = W_ih[r * 64 + d];
    s0 += w * W_emb[d * 2 + 0];
    s1 += w * W_emb[d * 2 + 1];
    sb += w * b_emb[d];
  }
  int q = r >> 7, j = r & 127;
  float sc = gate_scale(q);
  int np = (j >> 4) * 64 + q * 16 + (j & 15);
  biasp[np] = (b_ih[r] + b_hh[r] + sb) * sc;
  wx0p[np] = s0 * sc;
  wx1p[np] = s1 * sc;
}

// ---- prep 2: W_hh -> bf16 B-fragments (r6/r8/r10 mapping), PRE-SCALED ----
// frag f = g16*16 + q*4 + ks ; elem = (f*64 + lane)*8 + jj
// col n -> unit j = g16*16 + (lane&15), gate q => r = q*128 + g16*16 + cn
// k = ks*32 + (lane>>4)*8 + jj ; value = W_hh[r][k] * gate_scale(q)
__global__ void prep_wp(const float* __restrict__ W_hh, __bf16* __restrict__ Wp) {
  int tid = blockIdx.x * blockDim.x + threadIdx.x;  // 0..65535
  int jj = tid & 7;
  int lane = (tid >> 3) & 63;
  int frag = tid >> 9;  // 0..127
  int ks = frag & 3;
  int q = (frag >> 2) & 3;
  int g16 = frag >> 4;
  int cn = lane & 15, quad = lane >> 4;
  int r = q * 128 + g16 * 16 + cn;
  int k = ks * 32 + quad * 8 + jj;
  Wp[tid] = (__bf16)(W_hh[r * 128 + k] * gate_scale(q));
}

// ---- packed (f32x2) helpers: scalar transcendentals, VOP3P-packable arith ----
__device__ __forceinline__ f32x2 exp2_2(f32x2 v) {
  f32x2 r;
  r.x = exp2_hw(v.x);
  r.y = exp2_hw(v.y);
  return r;
}
__device__ __forceinline__ f32x2 rcp_2(f32x2 v) {
  f32x2 r;
  r.x = fast_rcp(v.x);
  r.y = fast_rcp(v.y);
  return r;
}

// lane-local LSTM cell on PRE-SCALED preacts, PAIRED over two adjacent
// accumulator rows (acc[u][q].xy or .zw — adjacent even-aligned VGPRs from
// the MFMA C-layout, so packing needs no cross-register moves):
//   c' = rcp((1+e_i)(1+e_g)(1+e_f)) * [ c*(1+e_i)(1+e_g) + (1-e_g)(1+e_f) ]
//   h  = (1-e_c) * rcp((1+e_o)(1+e_c))
// Same math as the scalar r5..r10 chain (absmax 1.95e-3); non-transcendental
// ops run as v_pk_{add,mul,fma}_f32, halving their issue count.
__device__ __forceinline__ f32x2 cell_update_pk(f32x2 gi, f32x2 gf, f32x2 gg,
                                                f32x2 go, f32x2& c) {
  f32x2 e_i = exp2_2(gi);
  f32x2 e_f = exp2_2(gf);
  f32x2 e_g = exp2_2(gg);
  f32x2 e_o = exp2_2(go);
  f32x2 a_i = e_i + 1.f;
  f32x2 a_f = e_f + 1.f;
  f32x2 a_g = e_g + 1.f;
  f32x2 bg = 1.f - e_g;  // == 2 - a_g
  f32x2 m1 = a_i * a_g;
  f32x2 r = rcp_2(m1 * a_f);
  f32x2 t = c * m1 + bg * a_f;  // contracts to v_pk_fma
  c = t * r;
  f32x2 e_c = exp2_2(c * (-2.f * LOG2E));
  f32x2 a_c = e_c + 1.f;
  f32x2 bc = 1.f - e_c;  // == 2 - a_c
  return bc * rcp_2((e_o + 1.f) * a_c);
}

// ---- main fused LSTM: 256 threads = 4 waves; wave wv owns unit-groups
// {2wv, 2wv+1} (r10 PROVEN). Merged-u step body: one shared A-load per ks,
// 32 MFMAs, then all 8 cell_updates as 4 packed pair-updates. Bias + wx
// tables hoisted to regs (8 + 16); c-state kept as f32x2 pairs matching the
// accumulator layout. ~252 unified regs <= 256 cap.
__global__ __launch_bounds__(256, 2) void lstm_fused(
    const float* __restrict__ obs, const float* __restrict__ h0,
    const float* __restrict__ c0, const __bf16* __restrict__ Wp,
    const float* __restrict__ biasp, const float* __restrict__ wx0p,
    const float* __restrict__ wx1p, float* __restrict__ out, int batch) {
  __shared__ __align__(16) __bf16 hbuf[2][MB][HSTR];
  __shared__ __align__(16) float obs_s[OBS_T][MB][2];

  const int tid = threadIdx.x;
  const int lane = tid & 63;
  const int wv = tid >> 6;  // 0..3
  const int cn = lane & 15;
  const int quad = lane >> 4;
  const int bbase = blockIdx.x * MB;
  const int ju0 = (wv * 2) * 16 + cn;  // unit-group 0 column

  // stage obs tile: [20][16][2] fp32 = 160 float4
  if (tid < OBS_T * MB * 2 / 4) {
    const int t = tid >> 3, f4 = tid & 7;
    ((float4*)obs_s)[tid] = ((const float4*)obs)[(t * batch + bbase) / 2 + f4];
  }
  // stage h0 tile fp32 -> bf16 LDS: 16 rows x 32 float4 = 512
#pragma unroll
  for (int it = 0; it < 2; ++it) {
    int idx = tid + it * 256;
    int row = idx >> 5, c4 = idx & 31;
    float4 v = ((const float4*)h0)[(bbase + row) * 32 + c4];
    bf16x4 b;
    b.x = (__bf16)v.x; b.y = (__bf16)v.y; b.z = (__bf16)v.z; b.w = (__bf16)v.w;
    *(bf16x4*)&hbuf[0][row][c4 * 4] = b;
  }

  // persistent B fragments: 2 unit-groups x 4 gates x 4 ksteps = 128 regs
  bf16x8 Bf[2][4][4];  // [u][ks][q]
  {
    const bf16x8* wp8 = (const bf16x8*)Wp;
#pragma unroll
    for (int u = 0; u < 2; ++u)
#pragma unroll
      for (int q = 0; q < 4; ++q)
#pragma unroll
        for (int ks = 0; ks < 4; ++ks)
          Bf[u][ks][q] = wp8[((wv * 2 + u) * 16 + q * 4 + ks) * 64 + lane];
  }

  // bias + rank-2 wx tables hoisted to regs (8 + 16): loop-invariant,
  // loaded straight from global (one-time, L2-cached) — no LDS round-trip.
  float bias_v[2][4], w0r[2][4], w1r[2][4];
#pragma unroll
  for (int u = 0; u < 2; ++u)
#pragma unroll
    for (int q = 0; q < 4; ++q) {
      int n = (wv * 2 + u) * 64 + q * 16 + cn;
      bias_v[u][q] = biasp[n];
      w0r[u][q] = wx0p[n];
      w1r[u][q] = wx1p[n];
    }

  // c state as f32x2 pairs: cc2[u][p] = c for rows (quad*4+2p, quad*4+2p+1)
  f32x2 cc2[2][2];
#pragma unroll
  for (int u = 0; u < 2; ++u)
#pragma unroll
    for (int p = 0; p < 2; ++p) {
      int ju = ju0 + u * 16;
      cc2[u][p].x = c0[(bbase + quad * 4 + 2 * p + 0) * HID + ju];
      cc2[u][p].y = c0[(bbase + quad * 4 + 2 * p + 1) * HID + ju];
    }

  __syncthreads();

  int cur = 0;
#pragma unroll 1
  for (int t = 0; t < OBS_T - 1; ++t) {
    // acc init for BOTH groups: bias + rank-2 folded embedding (fp32, pre-scaled)
    f32x4 acc[2][4];  // [u][q]
#pragma unroll
    for (int u = 0; u < 2; ++u)
#pragma unroll
      for (int q = 0; q < 4; ++q) {
        float w0q = w0r[u][q], w1q = w1r[u][q];
#pragma unroll
        for (int r = 0; r < 4; ++r) {
          float2 ob = *(const float2*)&obs_s[t][quad * 4 + r][0];
          acc[u][q][r] = fmaf(ob.y, w1q, fmaf(ob.x, w0q, bias_v[u][q]));
        }
      }

    // gates += h @ (scaled W_hh)^T : ONE A-load per ks, 32 MFMAs
#pragma unroll
    for (int ks = 0; ks < 4; ++ks) {
      bf16x8 Av = *(const bf16x8*)&hbuf[cur][cn][ks * 32 + quad * 8];
#pragma unroll
      for (int q = 0; q < 4; ++q) {
        acc[0][q] = __builtin_amdgcn_mfma_f32_16x16x32_bf16(Av, Bf[0][ks][q], acc[0][q], 0, 0, 0);
        acc[1][q] = __builtin_amdgcn_mfma_f32_16x16x32_bf16(Av, Bf[1][ks][q], acc[1][q], 0, 0, 0);
      }
    }

    // all 8 cell updates as 4 packed pair-updates (natural .xy/.zw pairs)
    const int nxt = cur ^ 1;
#pragma unroll
    for (int u = 0; u < 2; ++u) {
      const int ju = ju0 + u * 16;
      f32x2 hlo = cell_update_pk(acc[u][0].xy, acc[u][1].xy, acc[u][2].xy,
                                 acc[u][3].xy, cc2[u][0]);
      f32x2 hhi = cell_update_pk(acc[u][0].zw, acc[u][1].zw, acc[u][2].zw,
                                 acc[u][3].zw, cc2[u][1]);
      hbuf[nxt][quad * 4 + 0][ju] = (__bf16)hlo.x;
      hbuf[nxt][quad * 4 + 1][ju] = (__bf16)hlo.y;
      hbuf[nxt][quad * 4 + 2][ju] = (__bf16)hhi.x;
      hbuf[nxt][quad * 4 + 3][ju] = (__bf16)hhi.y;
    }
    __syncthreads();
    cur = nxt;
  }

  // peeled final step: h straight to global
  {
    const int t = OBS_T - 1;
    f32x4 acc[2][4];
#pragma unroll
    for (int u = 0; u < 2; ++u)
#pragma unroll
      for (int q = 0; q < 4; ++q) {
        float w0q = w0r[u][q], w1q = w1r[u][q];
#pragma unroll
        for (int r = 0; r < 4; ++r) {
          float2 ob = *(const float2*)&obs_s[t][quad * 4 + r][0];
          acc[u][q][r] = fmaf(ob.y, w1q, fmaf(ob.x, w0q, bias_v[u][q]));
        }
      }
#pragma unroll
    for (int ks = 0; ks < 4; ++ks) {
      bf16x8 Av = *(const bf16x8*)&hbuf[cur][cn][ks * 32 + quad * 8];
#pragma unroll
      for (int q = 0; q < 4; ++q) {
        acc[0][q] = __builtin_amdgcn_mfma_f32_16x16x32_bf16(Av, Bf[0][ks][q], acc[0][q], 0, 0, 0);
        acc[1][q] = __builtin_amdgcn_mfma_f32_16x16x32_bf16(Av, Bf[1][ks][q], acc[1][q], 0, 0, 0);
      }
    }
#pragma unroll
    for (int u = 0; u < 2; ++u) {
      const int ju = ju0 + u * 16;
      f32x2 hlo = cell_update_pk(acc[u][0].xy, acc[u][1].xy, acc[u][2].xy,
                                 acc[u][3].xy, cc2[u][0]);
      f32x2 hhi = cell_update_pk(acc[u][0].zw, acc[u][1].zw, acc[u][2].zw,
                                 acc[u][3].zw, cc2[u][1]);
      out[(bbase + quad * 4 + 0) * HID + ju] = hlo.x;
      out[(bbase + quad * 4 + 1) * HID + ju] = hlo.y;
      out[(bbase + quad * 4 + 2) * HID + ju] = hhi.x;
      out[(bbase + quad * 4 + 3) * HID + ju] = hhi.y;
    }
  }
}

extern "C" void kernel_launch(void* const* d_in, const int* in_sizes, int n_in,
                              void* d_out, int out_size, void* d_ws, size_t ws_size,
                              hipStream_t stream) {
  const float* obs = (const float*)d_in[0];
  const float* h0 = (const float*)d_in[1];
  const float* c0 = (const float*)d_in[2];
  const float* W_emb = (const float*)d_in[3];
  const float* b_emb = (const float*)d_in[4];
  const float* W_ih = (const float*)d_in[5];
  const float* W_hh = (const float*)d_in[6];
  const float* b_ih = (const float*)d_in[7];
  const float* b_hh = (const float*)d_in[8];
  float* out = (float*)d_out;
  const int batch = in_sizes[1] / HID;

  __bf16* Wp = (__bf16*)d_ws;                     // 65536 bf16 = 128 KB
  float* biasp = (float*)((char*)d_ws + 131072);  // 3 x 512 f32
  float* wx0p = biasp + NGATE;
  float* wx1p = wx0p + NGATE;

  prep_vec<<<2, 256, 0, stream>>>(W_emb, b_emb, W_ih, b_ih, b_hh, biasp, wx0p, wx1p);
  prep_wp<<<256, 256, 0, stream>>>(W_hh, Wp);
  lstm_fused<<<batch / MB, 256, 0, stream>>>(obs, h0, c0, Wp, biasp, wx0p, wx1p, out, batch);
}

// Round 2
// 336.624 us; speedup vs baseline: 1.4968x; 1.4968x over previous
//
#include <hip/hip_runtime.h>

#define OBS_T 20
#define HID 128
#define NGATE 512
#define MB 16          // batch rows per block
#define HSTR 136       // hbuf row stride in bf16 (272B = 17*16B)

typedef __bf16 bf16x8 __attribute__((ext_vector_type(8)));
typedef __bf16 bf16x4 __attribute__((ext_vector_type(4)));
typedef float f32x4 __attribute__((ext_vector_type(4)));
typedef float f32x2 __attribute__((ext_vector_type(2)));

__device__ __forceinline__ float fast_rcp(float x) { return __builtin_amdgcn_rcpf(x); }
#if __has_builtin(__builtin_amdgcn_exp2f)
__device__ __forceinline__ float exp2_hw(float x) { return __builtin_amdgcn_exp2f(x); }
#else
__device__ __forceinline__ float exp2_hw(float x) { return __expf(x * 0.69314718056f); }
#endif
#define LOG2E 1.442695041f

// gate scale: preacts arrive PRE-SCALED by s_q so exp2 needs no mul.
// s_q = -LOG2E for i,f,o ; -2*LOG2E for g (since tanh uses e^{-2x})
__device__ __host__ __forceinline__ float gate_scale(int q) {
  return (q == 2) ? (-2.0f * LOG2E) : (-LOG2E);
}

// ---- prep 1: fold embedding into rank-2 + bias, gate-major permutation ----
// gate row r = q*128 + j (torch i,f,g,o). np = (j>>4)*64 + q*16 + (j&15)
// SCALAR tables (r8/r10-proven; float4-packed variant failed twice — banned).
// Values pre-scaled by gate_scale(q).
__global__ void prep_vec(const float* __restrict__ W_emb, const float* __restrict__ b_emb,
                         const float* __restrict__ W_ih, const float* __restrict__ b_ih,
                         const float* __restrict__ b_hh,
                         float* __restrict__ biasp, float* __restrict__ wx0p,
                         float* __restrict__ wx1p) {
  int r = blockIdx.x * blockDim.x + threadIdx.x;
  if (r >= NGATE) return;
  float s0 = 0.f, s1 = 0.f, sb = 0.f;
  for (int d = 0; d < 64; ++d) {
    float w = W_ih[r * 64 + d];
    s0 += w * W_emb[d * 2 + 0];
    s1 += w * W_emb[d * 2 + 1];
    sb += w * b_emb[d];
  }
  int q = r >> 7, j = r & 127;
  float sc = gate_scale(q);
  int np = (j >> 4) * 64 + q * 16 + (j & 15);
  biasp[np] = (b_ih[r] + b_hh[r] + sb) * sc;
  wx0p[np] = s0 * sc;
  wx1p[np] = s1 * sc;
}

// ---- prep 2: W_hh -> bf16 B-fragments (r6/r8/r10 mapping), PRE-SCALED ----
// frag f = g16*16 + q*4 + ks ; elem = (f*64 + lane)*8 + jj
// col n -> unit j = g16*16 + (lane&15), gate q => r = q*128 + g16*16 + cn
// k = ks*32 + (lane>>4)*8 + jj ; value = W_hh[r][k] * gate_scale(q)
__global__ void prep_wp(const float* __restrict__ W_hh, __bf16* __restrict__ Wp) {
  int tid = blockIdx.x * blockDim.x + threadIdx.x;  // 0..65535
  int jj = tid & 7;
  int lane = (tid >> 3) & 63;
  int frag = tid >> 9;  // 0..127
  int ks = frag & 3;
  int q = (frag >> 2) & 3;
  int g16 = frag >> 4;
  int cn = lane & 15, quad = lane >> 4;
  int r = q * 128 + g16 * 16 + cn;
  int k = ks * 32 + quad * 8 + jj;
  Wp[tid] = (__bf16)(W_hh[r * 128 + k] * gate_scale(q));
}

// ---- packed (f32x2) helpers: scalar transcendentals, VOP3P-packable arith ----
__device__ __forceinline__ f32x2 exp2_2(f32x2 v) {
  f32x2 r;
  r.x = exp2_hw(v.x);
  r.y = exp2_hw(v.y);
  return r;
}
__device__ __forceinline__ f32x2 rcp_2(f32x2 v) {
  f32x2 r;
  r.x = fast_rcp(v.x);
  r.y = fast_rcp(v.y);
  return r;
}

// lane-local LSTM cell on PRE-SCALED preacts, PAIRED over two adjacent
// accumulator rows (acc[u][q].xy or .zw — adjacent even-aligned VGPRs from
// the MFMA C-layout, so packing needs no cross-register moves):
//   c' = rcp((1+e_i)(1+e_g)(1+e_f)) * [ c*(1+e_i)(1+e_g) + (1-e_g)(1+e_f) ]
//   h  = (1-e_c) * rcp((1+e_o)(1+e_c))
// Same math as the scalar r5..r10 chain (absmax 1.95e-3); non-transcendental
// ops run as v_pk_{add,mul,fma}_f32, halving their issue count.
// REG-NEUTRAL vs scalar form (same live values in the same aligned slots) —
// R1 proved the spill came from the +16-reg wx hoist, NOT from packing.
__device__ __forceinline__ f32x2 cell_update_pk(f32x2 gi, f32x2 gf, f32x2 gg,
                                                f32x2 go, f32x2& c) {
  f32x2 e_i = exp2_2(gi);
  f32x2 e_f = exp2_2(gf);
  f32x2 e_g = exp2_2(gg);
  f32x2 e_o = exp2_2(go);
  f32x2 a_i = e_i + 1.f;
  f32x2 a_f = e_f + 1.f;
  f32x2 a_g = e_g + 1.f;
  f32x2 bg = 1.f - e_g;  // == 2 - a_g
  f32x2 m1 = a_i * a_g;
  f32x2 r = rcp_2(m1 * a_f);
  f32x2 t = c * m1 + bg * a_f;  // contracts to v_pk_fma
  c = t * r;
  f32x2 e_c = exp2_2(c * (-2.f * LOG2E));
  f32x2 a_c = e_c + 1.f;
  f32x2 bc = 1.f - e_c;  // == 2 - a_c
  return bc * rcp_2((e_o + 1.f) * a_c);
}

// ---- main fused LSTM: 256 threads = 4 waves; wave wv owns unit-groups
// {2wv, 2wv+1} (r10 PROVEN). Merged-u step body: one shared A-load per ks,
// 32 MFMAs, then all 8 cell_updates as 4 packed pair-updates. Bias hoisted
// to regs (8); wx0/wx1 from scalar LDS tables (r8/r10-proven — hoisting them
// to regs = +16 regs = scratch spill, R1 FAILED, banned). c-state kept as
// f32x2 pairs matching the accumulator layout. ~252 unified regs <= 256 cap.
__global__ __launch_bounds__(256, 2) void lstm_fused(
    const float* __restrict__ obs, const float* __restrict__ h0,
    const float* __restrict__ c0, const __bf16* __restrict__ Wp,
    const float* __restrict__ biasp, const float* __restrict__ wx0p,
    const float* __restrict__ wx1p, float* __restrict__ out, int batch) {
  __shared__ __align__(16) __bf16 hbuf[2][MB][HSTR];
  __shared__ __align__(16) float obs_s[OBS_T][MB][2];
  __shared__ __align__(16) float wx0_s[NGATE];
  __shared__ __align__(16) float wx1_s[NGATE];

  const int tid = threadIdx.x;
  const int lane = tid & 63;
  const int wv = tid >> 6;  // 0..3
  const int cn = lane & 15;
  const int quad = lane >> 4;
  const int bbase = blockIdx.x * MB;
  const int ju0 = (wv * 2) * 16 + cn;  // unit-group 0 column

  // stage obs tile: [20][16][2] fp32 = 160 float4
  if (tid < OBS_T * MB * 2 / 4) {
    const int t = tid >> 3, f4 = tid & 7;
    ((float4*)obs_s)[tid] = ((const float4*)obs)[(t * batch + bbase) / 2 + f4];
  }
  // stage wx tables: 2 x 512 floats (scalar form — proven)
#pragma unroll
  for (int it = 0; it < 2; ++it) {
    int i = tid + it * 256;
    wx0_s[i] = wx0p[i];
    wx1_s[i] = wx1p[i];
  }
  // stage h0 tile fp32 -> bf16 LDS: 16 rows x 32 float4 = 512
#pragma unroll
  for (int it = 0; it < 2; ++it) {
    int idx = tid + it * 256;
    int row = idx >> 5, c4 = idx & 31;
    float4 v = ((const float4*)h0)[(bbase + row) * 32 + c4];
    bf16x4 b;
    b.x = (__bf16)v.x; b.y = (__bf16)v.y; b.z = (__bf16)v.z; b.w = (__bf16)v.w;
    *(bf16x4*)&hbuf[0][row][c4 * 4] = b;
  }

  // persistent B fragments: 2 unit-groups x 4 gates x 4 ksteps = 128 regs
  bf16x8 Bf[2][4][4];  // [u][ks][q]
  {
    const bf16x8* wp8 = (const bf16x8*)Wp;
#pragma unroll
    for (int u = 0; u < 2; ++u)
#pragma unroll
      for (int q = 0; q < 4; ++q)
#pragma unroll
        for (int ks = 0; ks < 4; ++ks)
          Bf[u][ks][q] = wp8[((wv * 2 + u) * 16 + q * 4 + ks) * 64 + lane];
  }

  // bias hoisted to regs (8): loop-invariant
  float bias_v[2][4];
#pragma unroll
  for (int u = 0; u < 2; ++u)
#pragma unroll
    for (int q = 0; q < 4; ++q)
      bias_v[u][q] = biasp[(wv * 2 + u) * 64 + q * 16 + cn];

  // c state as f32x2 pairs: cc2[u][p] = c for rows (quad*4+2p, quad*4+2p+1)
  f32x2 cc2[2][2];
#pragma unroll
  for (int u = 0; u < 2; ++u)
#pragma unroll
    for (int p = 0; p < 2; ++p) {
      int ju = ju0 + u * 16;
      cc2[u][p].x = c0[(bbase + quad * 4 + 2 * p + 0) * HID + ju];
      cc2[u][p].y = c0[(bbase + quad * 4 + 2 * p + 1) * HID + ju];
    }

  __syncthreads();

  int cur = 0;
#pragma unroll 1
  for (int t = 0; t < OBS_T - 1; ++t) {
    // acc init for BOTH groups: bias + rank-2 folded embedding (fp32, pre-scaled)
    f32x4 acc[2][4];  // [u][q]
#pragma unroll
    for (int u = 0; u < 2; ++u)
#pragma unroll
      for (int q = 0; q < 4; ++q) {
        int n = (wv * 2 + u) * 64 + q * 16 + cn;
        float w0q = wx0_s[n], w1q = wx1_s[n];
#pragma unroll
        for (int r = 0; r < 4; ++r) {
          float2 ob = *(const float2*)&obs_s[t][quad * 4 + r][0];
          acc[u][q][r] = fmaf(ob.y, w1q, fmaf(ob.x, w0q, bias_v[u][q]));
        }
      }

    // gates += h @ (scaled W_hh)^T : ONE A-load per ks, 32 MFMAs
#pragma unroll
    for (int ks = 0; ks < 4; ++ks) {
      bf16x8 Av = *(const bf16x8*)&hbuf[cur][cn][ks * 32 + quad * 8];
#pragma unroll
      for (int q = 0; q < 4; ++q) {
        acc[0][q] = __builtin_amdgcn_mfma_f32_16x16x32_bf16(Av, Bf[0][ks][q], acc[0][q], 0, 0, 0);
        acc[1][q] = __builtin_amdgcn_mfma_f32_16x16x32_bf16(Av, Bf[1][ks][q], acc[1][q], 0, 0, 0);
      }
    }

    // all 8 cell updates as 4 packed pair-updates (natural .xy/.zw pairs)
    const int nxt = cur ^ 1;
#pragma unroll
    for (int u = 0; u < 2; ++u) {
      const int ju = ju0 + u * 16;
      f32x2 hlo = cell_update_pk(acc[u][0].xy, acc[u][1].xy, acc[u][2].xy,
                                 acc[u][3].xy, cc2[u][0]);
      f32x2 hhi = cell_update_pk(acc[u][0].zw, acc[u][1].zw, acc[u][2].zw,
                                 acc[u][3].zw, cc2[u][1]);
      hbuf[nxt][quad * 4 + 0][ju] = (__bf16)hlo.x;
      hbuf[nxt][quad * 4 + 1][ju] = (__bf16)hlo.y;
      hbuf[nxt][quad * 4 + 2][ju] = (__bf16)hhi.x;
      hbuf[nxt][quad * 4 + 3][ju] = (__bf16)hhi.y;
    }
    __syncthreads();
    cur = nxt;
  }

  // peeled final step: h straight to global
  {
    const int t = OBS_T - 1;
    f32x4 acc[2][4];
#pragma unroll
    for (int u = 0; u < 2; ++u)
#pragma unroll
      for (int q = 0; q < 4; ++q) {
        int n = (wv * 2 + u) * 64 + q * 16 + cn;
        float w0q = wx0_s[n], w1q = wx1_s[n];
#pragma unroll
        for (int r = 0; r < 4; ++r) {
          float2 ob = *(const float2*)&obs_s[t][quad * 4 + r][0];
          acc[u][q][r] = fmaf(ob.y, w1q, fmaf(ob.x, w0q, bias_v[u][q]));
        }
      }
#pragma unroll
    for (int ks = 0; ks < 4; ++ks) {
      bf16x8 Av = *(const bf16x8*)&hbuf[cur][cn][ks * 32 + quad * 8];
#pragma unroll
      for (int q = 0; q < 4; ++q) {
        acc[0][q] = __builtin_amdgcn_mfma_f32_16x16x32_bf16(Av, Bf[0][ks][q], acc[0][q], 0, 0, 0);
        acc[1][q] = __builtin_amdgcn_mfma_f32_16x16x32_bf16(Av, Bf[1][ks][q], acc[1][q], 0, 0, 0);
      }
    }
#pragma unroll
    for (int u = 0; u < 2; ++u) {
      const int ju = ju0 + u * 16;
      f32x2 hlo = cell_update_pk(acc[u][0].xy, acc[u][1].xy, acc[u][2].xy,
                                 acc[u][3].xy, cc2[u][0]);
      f32x2 hhi = cell_update_pk(acc[u][0].zw, acc[u][1].zw, acc[u][2].zw,
                                 acc[u][3].zw, cc2[u][1]);
      out[(bbase + quad * 4 + 0) * HID + ju] = hlo.x;
      out[(bbase + quad * 4 + 1) * HID + ju] = hlo.y;
      out[(bbase + quad * 4 + 2) * HID + ju] = hhi.x;
      out[(bbase + quad * 4 + 3) * HID + ju] = hhi.y;
    }
  }
}

extern "C" void kernel_launch(void* const* d_in, const int* in_sizes, int n_in,
                              void* d_out, int out_size, void* d_ws, size_t ws_size,
                              hipStream_t stream) {
  const float* obs = (const float*)d_in[0];
  const float* h0 = (const float*)d_in[1];
  const float* c0 = (const float*)d_in[2];
  const float* W_emb = (const float*)d_in[3];
  const float* b_emb = (const float*)d_in[4];
  const float* W_ih = (const float*)d_in[5];
  const float* W_hh = (const float*)d_in[6];
  const float* b_ih = (const float*)d_in[7];
  const float* b_hh = (const float*)d_in[8];
  float* out = (float*)d_out;
  const int batch = in_sizes[1] / HID;

  __bf16* Wp = (__bf16*)d_ws;                     // 65536 bf16 = 128 KB
  float* biasp = (float*)((char*)d_ws + 131072);  // 3 x 512 f32
  float* wx0p = biasp + NGATE;
  float* wx1p = wx0p + NGATE;

  prep_vec<<<2, 256, 0, stream>>>(W_emb, b_emb, W_ih, b_ih, b_hh, biasp, wx0p, wx1p);
  prep_wp<<<256, 256, 0, stream>>>(W_hh, Wp);
  lstm_fused<<<batch / MB, 256, 0, stream>>>(obs, h0, c0, Wp, biasp, wx0p, wx1p, out, batch);
}